// Round 1
// 236.356 us; speedup vs baseline: 1.0261x; 1.0261x over previous
//
#include <hip/hip_runtime.h>
#include <math.h>

#define BB     32
#define KMAX   2048
#define QDIM   512
#define VDIM   512
#define NMIX   8
#define EPSV   1e-6f
#define NEGINF -3.40282347e38f
#define TWO_PI 6.28318530717958647692f
#define SUBS   8
#define KSUB   (KMAX / SUBS)     // 256 k's per block == blockDim
#define AW_SKIP_EPS 1e-12f

// Single fused kernel: grid = BB*SUBS (256 blocks = 1/CU) x 256 threads.
// Per block: compute the 24 q-projections -> 8 Gaussian params, one aw per
// thread (coalesced store), ballot-compact the active k's (|aw| >= 1e-12;
// NEG_INF masked entries are always active, matching the reference einsum),
// then stream only active value rows with 4-deep independent float2 loads
// and atomically accumulate into cv (pre-zeroed by a 64 KB memset).
__global__ __launch_bounds__(256) void gmm_fused_kernel(
    const float* __restrict__ query,
    const int*   __restrict__ mask,
    const float* __restrict__ Wg, const float* __restrict__ bg,
    const float* __restrict__ Wb, const float* __restrict__ bb,
    const float* __restrict__ Wk, const float* __restrict__ bk,
    const float* __restrict__ value,
    float* __restrict__ cv,      // [B][VDIM], pre-zeroed via hipMemsetAsync
    float* __restrict__ aw_out)  // [B][KMAX]
{
    int blk  = blockIdx.x;
    int b    = blk >> 3;          // / SUBS
    int sub  = blk & (SUBS - 1);
    int t    = threadIdx.x;       // 256 threads = 4 waves
    int wave = t >> 6, lane = t & 63;

    __shared__ float dots[24];
    __shared__ float p[24];   // [0..7]=myu [8..15]=1/(2v+eps) [16..23]=w*rsqrt(2pi*v+eps)
    __shared__ float aw_s[KSUB];
    __shared__ unsigned long long bal[4];
    __shared__ int   klist[KSUB];
    __shared__ int   nk;

    // ---- 24 dot products: q[b] . W_{gamma,beta,kappa}[m] (6 per wave) ----
    const float4* q4 = (const float4*)(query + (size_t)b * QDIM);
    float4 a0 = q4[lane];
    float4 a1 = q4[lane + 64];
    for (int j = wave; j < 24; j += 4) {
        int set = j >> 3, m = j & 7;
        const float* Wrow = (set == 0 ? Wg : (set == 1 ? Wb : Wk)) + (size_t)m * QDIM;
        const float4* W4 = (const float4*)Wrow;
        float4 w0 = W4[lane], w1 = W4[lane + 64];
        float ss = a0.x * w0.x + a0.y * w0.y + a0.z * w0.z + a0.w * w0.w
                 + a1.x * w1.x + a1.y * w1.y + a1.z * w1.z + a1.w * w1.w;
        #pragma unroll
        for (int off = 32; off; off >>= 1) ss += __shfl_down(ss, off, 64);
        if (lane == 0) dots[j] = ss;
    }
    __syncthreads();

    if (t == 0) {
        float g[8], mx = -1e30f;
        #pragma unroll
        for (int m = 0; m < 8; m++) { g[m] = dots[m] + bg[m]; mx = fmaxf(mx, g[m]); }
        float sum = 0.f;
        #pragma unroll
        for (int m = 0; m < 8; m++) { g[m] = expf(g[m] - mx); sum += g[m]; }
        float inv_sum = 1.f / sum;
        #pragma unroll
        for (int m = 0; m < 8; m++) {
            float w   = g[m] * inv_sum;
            float v   = expf(dots[8 + m]  + bb[m]);
            float myu = expf(dots[16 + m] + bk[m]);
            p[m]      = myu;
            p[8 + m]  = 1.f / (2.f * v + EPSV);
            p[16 + m] = w * rsqrtf(TWO_PI * v + EPSV);
        }
    }
    __syncthreads();

    // ---- one aw per thread (coalesced store + LDS copy) ----
    int k = sub * KSUB + t;
    float fj = (float)k;
    float aw = 0.f;
    #pragma unroll
    for (int m = 0; m < 8; m++) {
        float d = fj - p[m];
        aw += p[16 + m] * expf(-d * d * p[8 + m]);
    }
    if (mask[(size_t)b * KMAX + k] == 0) aw = NEGINF;
    aw_out[(size_t)b * KMAX + k] = aw;
    aw_s[t] = aw;

    unsigned long long bm = __ballot(fabsf(aw) >= AW_SKIP_EPS);
    if (lane == 0) bal[wave] = bm;
    __syncthreads();

    // Block-uniform early exit (reads identical LDS values in every thread).
    if ((bal[0] | bal[1] | bal[2] | bal[3]) == 0ULL) return;

    // ---- compact active-k list (thread 0, ~tens of entries) ----
    if (t == 0) {
        int n = 0;
        #pragma unroll
        for (int w = 0; w < 4; w++) {
            unsigned long long mbits = bal[w];
            while (mbits) {
                int i = __builtin_ctzll(mbits);
                mbits &= mbits - 1;
                klist[n++] = w * 64 + i;
            }
        }
        nk = n;
    }
    __syncthreads();

    // ---- accumulate cv over active rows: 4 independent loads in flight ----
    int n = nk;
    const float* vbase = value + ((size_t)b * KMAX + sub * KSUB) * VDIM;
    float2 acc = make_float2(0.f, 0.f);
    int i = 0;
    for (; i + 4 <= n; i += 4) {
        int kA = klist[i], kB = klist[i + 1], kC = klist[i + 2], kD = klist[i + 3];
        float aA = aw_s[kA], aB = aw_s[kB], aC = aw_s[kC], aD = aw_s[kD];
        float2 vA = ((const float2*)(vbase + (size_t)kA * VDIM))[t];
        float2 vB = ((const float2*)(vbase + (size_t)kB * VDIM))[t];
        float2 vC = ((const float2*)(vbase + (size_t)kC * VDIM))[t];
        float2 vD = ((const float2*)(vbase + (size_t)kD * VDIM))[t];
        acc.x += aA * vA.x; acc.y += aA * vA.y;
        acc.x += aB * vB.x; acc.y += aB * vB.y;
        acc.x += aC * vC.x; acc.y += aC * vC.y;
        acc.x += aD * vD.x; acc.y += aD * vD.y;
    }
    for (; i < n; i++) {
        int kk = klist[i];
        float a = aw_s[kk];
        float2 v = ((const float2*)(vbase + (size_t)kk * VDIM))[t];
        acc.x += a * v.x; acc.y += a * v.y;
    }
    float* cvp = cv + (size_t)b * VDIM + t * 2;
    atomicAdd(cvp + 0, acc.x);
    atomicAdd(cvp + 1, acc.y);
}

extern "C" void kernel_launch(void* const* d_in, const int* in_sizes, int n_in,
                              void* d_out, int out_size, void* d_ws, size_t ws_size,
                              hipStream_t stream) {
    // inputs: 0 key_feat (UNUSED), 1 value, 2 query, 3 mask,
    //         4 W_gamma, 5 b_gamma, 6 W_beta, 7 b_beta, 8 W_kappa, 9 b_kappa
    const float* value = (const float*)d_in[1];
    const float* query = (const float*)d_in[2];
    const int*   mask  = (const int*)d_in[3];
    const float* Wg = (const float*)d_in[4];
    const float* bg = (const float*)d_in[5];
    const float* Wb = (const float*)d_in[6];
    const float* bb = (const float*)d_in[7];
    const float* Wk = (const float*)d_in[8];
    const float* bk = (const float*)d_in[9];

    float* out = (float*)d_out;
    float* cv  = out;                 // [B][VDIM]  = 16384 floats
    float* aw  = out + BB * VDIM;     // [B][KMAX]  = 65536 floats

    hipMemsetAsync(cv, 0, (size_t)BB * VDIM * sizeof(float), stream);
    gmm_fused_kernel<<<BB * SUBS, 256, 0, stream>>>(
        query, mask, Wg, bg, Wb, bb, Wk, bk, value, cv, aw);
}

// Round 2
// 230.942 us; speedup vs baseline: 1.0501x; 1.0234x over previous
//
#include <hip/hip_runtime.h>
#include <math.h>

#define BB     32
#define KMAX   2048
#define QDIM   512
#define VDIM   512
#define NMIX   8
#define EPSV   1e-6f
#define NEGINF -3.40282347e38f
#define TWO_PI 6.28318530717958647692f
#define NT     1024
#define NWAVE  (NT / 64)         // 16 waves
#define NPAIR  (KMAX / 2)        // 1024 k-pairs, one per thread
#define CVGRP  4                 // 4 groups x 256 threads for the cv loop
#define AW_SKIP_EPS 1e-12f

// Single dispatch: grid = BB (32) blocks x 1024 threads, one block per batch.
// Phase 1: 24 q-projections -> 8 Gaussian params.
// Phase 2: each thread computes aw for 2 adjacent k's, stores float2
//          (coalesced) + LDS copy; ballot over k-pairs marks active pairs
//          (|aw| >= 1e-12; NEG_INF masked entries always active -> exact
//          match with the reference einsum; skipped pairs contribute
//          <= 1e-12 * 2048 * |v| ~ 2e-9, far below tolerance).
// Phase 3: 4 thread-groups stream the active value rows (2-pair unroll =
//          4 independent float2 loads in flight), LDS-reduce the 4 partials,
//          store cv directly — no atomics, no memset, no second dispatch.
//          If nothing is active the partials are zero and cv gets zeros.
__global__ __launch_bounds__(1024) void gmm_fused_kernel(
    const float* __restrict__ query,
    const int*   __restrict__ mask,
    const float* __restrict__ Wg, const float* __restrict__ bg,
    const float* __restrict__ Wb, const float* __restrict__ bb,
    const float* __restrict__ Wk, const float* __restrict__ bk,
    const float* __restrict__ value,
    float* __restrict__ cv,      // [B][VDIM]
    float* __restrict__ aw_out)  // [B][KMAX]
{
    int b    = blockIdx.x;
    int t    = threadIdx.x;
    int wave = t >> 6, lane = t & 63;

    __shared__ float dots[24];
    __shared__ float p[24];   // [0..7]=myu [8..15]=1/(2v+eps) [16..23]=w*rsqrt(2pi*v+eps)
    __shared__ float aw_s[KMAX];
    __shared__ unsigned long long bal[NWAVE];
    __shared__ short plist[NPAIR];
    __shared__ int   np;
    __shared__ float partial[CVGRP][VDIM];

    // ---- 24 dot products: q[b] . W_{gamma,beta,kappa}[m] ----
    const float4* q4 = (const float4*)(query + (size_t)b * QDIM);
    float4 a0 = q4[lane];
    float4 a1 = q4[lane + 64];
    for (int j = wave; j < 24; j += NWAVE) {
        int set = j >> 3, m = j & 7;
        const float* Wrow = (set == 0 ? Wg : (set == 1 ? Wb : Wk)) + (size_t)m * QDIM;
        const float4* W4 = (const float4*)Wrow;
        float4 w0 = W4[lane], w1 = W4[lane + 64];
        float ss = a0.x * w0.x + a0.y * w0.y + a0.z * w0.z + a0.w * w0.w
                 + a1.x * w1.x + a1.y * w1.y + a1.z * w1.z + a1.w * w1.w;
        #pragma unroll
        for (int off = 32; off; off >>= 1) ss += __shfl_down(ss, off, 64);
        if (lane == 0) dots[j] = ss;
    }
    __syncthreads();

    if (t == 0) {
        float g[8], mx = -1e30f;
        #pragma unroll
        for (int m = 0; m < 8; m++) { g[m] = dots[m] + bg[m]; mx = fmaxf(mx, g[m]); }
        float sum = 0.f;
        #pragma unroll
        for (int m = 0; m < 8; m++) { g[m] = expf(g[m] - mx); sum += g[m]; }
        float inv_sum = 1.f / sum;
        #pragma unroll
        for (int m = 0; m < 8; m++) {
            float w   = g[m] * inv_sum;
            float v   = expf(dots[8 + m]  + bb[m]);
            float myu = expf(dots[16 + m] + bk[m]);
            p[m]      = myu;
            p[8 + m]  = 1.f / (2.f * v + EPSV);
            p[16 + m] = w * rsqrtf(TWO_PI * v + EPSV);
        }
    }
    __syncthreads();

    // ---- aw for 2 adjacent k's per thread (float2 coalesced store) ----
    int k0 = 2 * t;
    float f0 = (float)k0, f1 = (float)(k0 + 1);
    float aw0 = 0.f, aw1 = 0.f;
    #pragma unroll
    for (int m = 0; m < 8; m++) {
        float s  = p[16 + m], q2 = p[8 + m], mu = p[m];
        float d0 = f0 - mu, d1 = f1 - mu;
        aw0 += s * expf(-d0 * d0 * q2);
        aw1 += s * expf(-d1 * d1 * q2);
    }
    int2 mk = ((const int2*)(mask + (size_t)b * KMAX))[t];
    if (mk.x == 0) aw0 = NEGINF;
    if (mk.y == 0) aw1 = NEGINF;
    ((float2*)(aw_out + (size_t)b * KMAX))[t] = make_float2(aw0, aw1);
    aw_s[k0]     = aw0;
    aw_s[k0 + 1] = aw1;

    unsigned long long bm =
        __ballot(fabsf(aw0) >= AW_SKIP_EPS || fabsf(aw1) >= AW_SKIP_EPS);
    if (lane == 0) bal[wave] = bm;
    __syncthreads();

    // ---- compact active-pair list (thread 0, typically ~25 entries) ----
    if (t == 0) {
        int n = 0;
        #pragma unroll
        for (int w = 0; w < NWAVE; w++) {
            unsigned long long mbits = bal[w];
            while (mbits) {
                int i = __builtin_ctzll(mbits);
                mbits &= mbits - 1;
                plist[n++] = (short)(w * 64 + i);
            }
        }
        np = n;
    }
    __syncthreads();

    // ---- cv: 4 groups stream active rows, 4 float2 loads in flight ----
    int n   = np;
    int grp = t >> 8;        // 0..3
    int d2  = t & 255;       // float2 slot within the 512-dim row
    const float* vbase = value + (size_t)b * KMAX * VDIM;
    float2 acc = make_float2(0.f, 0.f);
    int i = grp;
    for (; i + CVGRP < n; i += 2 * CVGRP) {
        int pkA = plist[i], pkB = plist[i + CVGRP];
        int kA0 = 2 * pkA, kA1 = kA0 + 1;
        int kB0 = 2 * pkB, kB1 = kB0 + 1;
        float aA0 = aw_s[kA0], aA1 = aw_s[kA1];
        float aB0 = aw_s[kB0], aB1 = aw_s[kB1];
        float2 vA0 = ((const float2*)(vbase + (size_t)kA0 * VDIM))[d2];
        float2 vA1 = ((const float2*)(vbase + (size_t)kA1 * VDIM))[d2];
        float2 vB0 = ((const float2*)(vbase + (size_t)kB0 * VDIM))[d2];
        float2 vB1 = ((const float2*)(vbase + (size_t)kB1 * VDIM))[d2];
        acc.x += aA0 * vA0.x + aA1 * vA1.x + aB0 * vB0.x + aB1 * vB1.x;
        acc.y += aA0 * vA0.y + aA1 * vA1.y + aB0 * vB0.y + aB1 * vB1.y;
    }
    for (; i < n; i += CVGRP) {
        int pk = plist[i];
        int ka = 2 * pk, kb2 = ka + 1;
        float a0s = aw_s[ka], a1s = aw_s[kb2];
        float2 v0 = ((const float2*)(vbase + (size_t)ka  * VDIM))[d2];
        float2 v1 = ((const float2*)(vbase + (size_t)kb2 * VDIM))[d2];
        acc.x += a0s * v0.x + a1s * v1.x;
        acc.y += a0s * v0.y + a1s * v1.y;
    }
    ((float2*)&partial[grp][0])[d2] = acc;
    __syncthreads();

    // ---- reduce 4 partials, store cv (zeros if nothing active) ----
    if (t < 256) {
        float2 s0 = ((const float2*)&partial[0][0])[t];
        float2 s1 = ((const float2*)&partial[1][0])[t];
        float2 s2 = ((const float2*)&partial[2][0])[t];
        float2 s3 = ((const float2*)&partial[3][0])[t];
        ((float2*)(cv + (size_t)b * VDIM))[t] =
            make_float2(s0.x + s1.x + s2.x + s3.x, s0.y + s1.y + s2.y + s3.y);
    }
}

extern "C" void kernel_launch(void* const* d_in, const int* in_sizes, int n_in,
                              void* d_out, int out_size, void* d_ws, size_t ws_size,
                              hipStream_t stream) {
    // inputs: 0 key_feat (UNUSED), 1 value, 2 query, 3 mask,
    //         4 W_gamma, 5 b_gamma, 6 W_beta, 7 b_beta, 8 W_kappa, 9 b_kappa
    const float* value = (const float*)d_in[1];
    const float* query = (const float*)d_in[2];
    const int*   mask  = (const int*)d_in[3];
    const float* Wg = (const float*)d_in[4];
    const float* bg = (const float*)d_in[5];
    const float* Wb = (const float*)d_in[6];
    const float* bb = (const float*)d_in[7];
    const float* Wk = (const float*)d_in[8];
    const float* bk = (const float*)d_in[9];

    float* out = (float*)d_out;
    float* cv  = out;                 // [B][VDIM]  = 16384 floats
    float* aw  = out + BB * VDIM;     // [B][KMAX]  = 65536 floats

    gmm_fused_kernel<<<BB, NT, 0, stream>>>(
        query, mask, Wg, bg, Wb, bb, Wk, bk, value, cv, aw);
}